// Round 5
// baseline (40.414 us; speedup 1.0000x reference)
//
#include <hip/hip_runtime.h>

#define NUF 100000
#define NIF 100000
#define DIM 64
#define LNZ 32
#define NB 16384
#define NI 16384
#define OUTW 66   // D + 2

// round-to-nearest-even f32 -> bf16 (no NaN handling needed for this data)
static __device__ __forceinline__ unsigned short f2bf(float x) {
    unsigned u = __float_as_uint(x);
    return (unsigned short)((u + 0x7FFFu + ((u >> 16) & 1u)) >> 16);
}
static __device__ __forceinline__ float bf2f(unsigned short b) {
    return __uint_as_float((unsigned)b << 16);
}

// ---------------- Kernel A: f32 tables -> bf16 rows in ws ----------------
// ws layout: [NUF rows x 128B][NIF rows x 128B]; 8 f32 -> 8 bf16 per thread.
__global__ __launch_bounds__(256) void cvt_kernel(
    const float* __restrict__ ue, const float* __restrict__ ie,
    unsigned short* __restrict__ wsb)
{
    const size_t oct = (size_t)blockIdx.x * blockDim.x + threadIdx.x;
    const size_t uOct = (size_t)NUF * DIM / 8;          // 800000
    const size_t nOct = (size_t)(NUF + NIF) * DIM / 8;  // 1600000
    if (oct >= nOct) return;
    const float* src = (oct < uOct) ? (ue + oct * 8) : (ie + (oct - uOct) * 8);
    float a0 = __builtin_nontemporal_load(src + 0);
    float a1 = __builtin_nontemporal_load(src + 1);
    float a2 = __builtin_nontemporal_load(src + 2);
    float a3 = __builtin_nontemporal_load(src + 3);
    float a4 = __builtin_nontemporal_load(src + 4);
    float a5 = __builtin_nontemporal_load(src + 5);
    float a6 = __builtin_nontemporal_load(src + 6);
    float a7 = __builtin_nontemporal_load(src + 7);
    uint4 p;
    p.x = (unsigned)f2bf(a0) | ((unsigned)f2bf(a1) << 16);
    p.y = (unsigned)f2bf(a2) | ((unsigned)f2bf(a3) << 16);
    p.z = (unsigned)f2bf(a4) | ((unsigned)f2bf(a5) << 16);
    p.w = (unsigned)f2bf(a6) | ((unsigned)f2bf(a7) << 16);
    *reinterpret_cast<uint4*>(wsb + oct * 8) = p;   // regular store: keep in cache
}

// ---------------- Kernel B: gather from bf16 rows (one L2 line each) -----
// 4 rows per wave: 16-lane group per row, lane owns dims 4t..4t+3.
// XCD side-shard: (blockIdx&7)<4 -> users, else items.
__global__ __launch_bounds__(256) void ensfm_bf16_kernel(
    const unsigned short* __restrict__ wsb,  // bf16 tables
    const float* __restrict__ w_user,
    const float* __restrict__ w_item,
    const float* __restrict__ gbias,
    const float* __restrict__ h1,
    const float* __restrict__ h2,
    const int*   __restrict__ u_idx,
    const int*   __restrict__ i_idx,
    float* __restrict__ out)
{
    const int lane = threadIdx.x & 63;
    const int wib  = threadIdx.x >> 6;
    const int g    = lane >> 4;
    const int t    = lane & 15;

    if (blockIdx.x == 0 && threadIdx.x < DIM) {
        out[(size_t)(NB + NI) * OUTW + threadIdx.x] = h2[threadIdx.x];
    }

    const int xcd      = blockIdx.x & 7;
    const bool is_user = (xcd < 4);
    const int sideblk  = (blockIdx.x >> 3) * 4 + (xcd & 3);
    const int r        = sideblk * 16 + wib * 4 + g;      // 0..16383

    const unsigned short* emb = is_user ? wsb : (wsb + (size_t)NUF * DIM);
    const float* wtab = is_user ? w_user : w_item;
    const int*   idxp = is_user ? u_idx  : i_idx;

    const int* ibase = idxp + (size_t)r * LNZ + 2 * t;
    int2 myidx;
    myidx.x = __builtin_nontemporal_load(ibase);
    myidx.y = __builtin_nontemporal_load(ibase + 1);

    float wsum = wtab[myidx.x] + wtab[myidx.y];
    #pragma unroll
    for (int m = 1; m < 16; m <<= 1) wsum += __shfl_xor(wsum, m, 64);

    float4 su = {0.f, 0.f, 0.f, 0.f};
    float4 ss = {0.f, 0.f, 0.f, 0.f};
    const int gbase = lane & 48;
    #pragma unroll
    for (int l = 0; l < LNZ; ++l) {
        const int idx = __shfl((l & 1) ? myidx.y : myidx.x, gbase | (l >> 1), 64);
        const ushort4 ev = *reinterpret_cast<const ushort4*>(emb + (size_t)idx * DIM + 4 * t);
        const float ex = bf2f(ev.x), ey = bf2f(ev.y), ez = bf2f(ev.z), ew = bf2f(ev.w);
        su.x += ex; su.y += ey; su.z += ez; su.w += ew;
        ss.x = fmaf(ex, ex, ss.x);
        ss.y = fmaf(ey, ey, ss.y);
        ss.z = fmaf(ez, ez, ss.z);
        ss.w = fmaf(ew, ew, ss.w);
    }

    const float4 h1v = *reinterpret_cast<const float4*>(h1 + 4 * t);
    float dot = 0.5f * (su.x * su.x - ss.x) * h1v.x
              + 0.5f * (su.y * su.y - ss.y) * h1v.y
              + 0.5f * (su.z * su.z - ss.z) * h1v.z
              + 0.5f * (su.w * su.w - ss.w) * h1v.w;
    #pragma unroll
    for (int m = 1; m < 16; m <<= 1) dot += __shfl_xor(dot, m, 64);

    const float scal = dot + wsum + (is_user ? gbias[0] : 0.0f);

    const int orow_i = is_user ? r : (NB + r);
    float* orow = out + (size_t)orow_i * OUTW;
    __builtin_nontemporal_store(su.x, orow + 4 * t);
    __builtin_nontemporal_store(su.y, orow + 4 * t + 1);
    __builtin_nontemporal_store(su.z, orow + 4 * t + 2);
    __builtin_nontemporal_store(su.w, orow + 4 * t + 3);
    if (t == 0) {
        if (is_user) {
            __builtin_nontemporal_store(scal, orow + DIM);
            __builtin_nontemporal_store(1.0f, orow + DIM + 1);
        } else {
            __builtin_nontemporal_store(1.0f, orow + DIM);
            __builtin_nontemporal_store(scal, orow + DIM + 1);
        }
    }
}

// ---------------- Fallback: f32 gather (if ws too small) -----------------
__global__ __launch_bounds__(256) void ensfm_f32_kernel(
    const float* __restrict__ ue_emb, const float* __restrict__ ie_emb,
    const float* __restrict__ w_user, const float* __restrict__ w_item,
    const float* __restrict__ gbias,  const float* __restrict__ h1,
    const float* __restrict__ h2,
    const int* __restrict__ u_idx, const int* __restrict__ i_idx,
    float* __restrict__ out)
{
    const int lane = threadIdx.x & 63;
    const int wib  = threadIdx.x >> 6;
    const int g    = lane >> 4;
    const int t    = lane & 15;
    if (blockIdx.x == 0 && threadIdx.x < DIM)
        out[(size_t)(NB + NI) * OUTW + threadIdx.x] = h2[threadIdx.x];
    const int xcd      = blockIdx.x & 7;
    const bool is_user = (xcd < 4);
    const int sideblk  = (blockIdx.x >> 3) * 4 + (xcd & 3);
    const int r        = sideblk * 16 + wib * 4 + g;
    const float* emb  = is_user ? ue_emb : ie_emb;
    const float* wtab = is_user ? w_user : w_item;
    const int*   idxp = is_user ? u_idx  : i_idx;
    const int2 myidx = *reinterpret_cast<const int2*>(idxp + (size_t)r * LNZ + 2 * t);
    float wsum = wtab[myidx.x] + wtab[myidx.y];
    #pragma unroll
    for (int m = 1; m < 16; m <<= 1) wsum += __shfl_xor(wsum, m, 64);
    float4 su = {0.f,0.f,0.f,0.f}, ss = {0.f,0.f,0.f,0.f};
    const int gbase = lane & 48;
    #pragma unroll
    for (int l = 0; l < LNZ; ++l) {
        const int idx = __shfl((l & 1) ? myidx.y : myidx.x, gbase | (l >> 1), 64);
        const float4 e = *reinterpret_cast<const float4*>(emb + (size_t)idx * DIM + 4 * t);
        su.x += e.x; su.y += e.y; su.z += e.z; su.w += e.w;
        ss.x = fmaf(e.x,e.x,ss.x); ss.y = fmaf(e.y,e.y,ss.y);
        ss.z = fmaf(e.z,e.z,ss.z); ss.w = fmaf(e.w,e.w,ss.w);
    }
    const float4 h1v = *reinterpret_cast<const float4*>(h1 + 4 * t);
    float dot = 0.5f*(su.x*su.x-ss.x)*h1v.x + 0.5f*(su.y*su.y-ss.y)*h1v.y
              + 0.5f*(su.z*su.z-ss.z)*h1v.z + 0.5f*(su.w*su.w-ss.w)*h1v.w;
    #pragma unroll
    for (int m = 1; m < 16; m <<= 1) dot += __shfl_xor(dot, m, 64);
    const float scal = dot + wsum + (is_user ? gbias[0] : 0.0f);
    const int orow_i = is_user ? r : (NB + r);
    float* orow = out + (size_t)orow_i * OUTW;
    orow[4*t] = su.x; orow[4*t+1] = su.y; orow[4*t+2] = su.z; orow[4*t+3] = su.w;
    if (t == 0) {
        if (is_user) { orow[DIM] = scal; orow[DIM+1] = 1.0f; }
        else         { orow[DIM] = 1.0f; orow[DIM+1] = scal; }
    }
}

extern "C" void kernel_launch(void* const* d_in, const int* in_sizes, int n_in,
                              void* d_out, int out_size, void* d_ws, size_t ws_size,
                              hipStream_t stream) {
    const float* ue_emb = (const float*)d_in[0];
    const float* ie_emb = (const float*)d_in[1];
    const float* w_user = (const float*)d_in[2];
    const float* w_item = (const float*)d_in[3];
    const float* gbias  = (const float*)d_in[4];
    const float* h1     = (const float*)d_in[5];
    const float* h2     = (const float*)d_in[6];
    const int*   u_idx  = (const int*)d_in[7];
    const int*   i_idx  = (const int*)d_in[8];
    float* out = (float*)d_out;

    const size_t need = (size_t)(NUF + NIF) * DIM * 2;   // 25.6 MB bf16 tables
    const int blocks = (NB + NI) / 16;                   // 2048

    if (ws_size >= need && d_ws != nullptr) {
        unsigned short* wsb = (unsigned short*)d_ws;
        const int cvt_threads = (NUF + NIF) * DIM / 8;   // 1,600,000
        cvt_kernel<<<(cvt_threads + 255) / 256, 256, 0, stream>>>(ue_emb, ie_emb, wsb);
        ensfm_bf16_kernel<<<blocks, 256, 0, stream>>>(
            wsb, w_user, w_item, gbias, h1, h2, u_idx, i_idx, out);
    } else {
        ensfm_f32_kernel<<<blocks, 256, 0, stream>>>(
            ue_emb, ie_emb, w_user, w_item, gbias, h1, h2, u_idx, i_idx, out);
    }
}